// Round 1
// baseline (3436.726 us; speedup 1.0000x reference)
//
#include <hip/hip_runtime.h>

#define N_    16
#define DIN   24
#define DOUT  26
#define CIN   64
#define COUT  128
#define NGRP  8
#define EPS   1e-5f

// ws layout: float ws[N_][NGRP][2]  (sum, sumsq) -- must be zeroed every launch
__global__ void zero_ws_kernel(float* ws) {
    int i = blockIdx.x * blockDim.x + threadIdx.x;
    if (i < N_ * NGRP * 2) ws[i] = 0.0f;
}

// One block per output row (n, d, h). 256 threads.
// thread: cg = tid&31 -> co = cg*4..cg*4+3 ;  pg = tid>>5 -> w in {pg, pg+8, pg+16, pg+24}
__global__ __launch_bounds__(256, 2) void conv_relu_sum_kernel(
    const float* __restrict__ x, const float* __restrict__ K,
    float* __restrict__ y, float* __restrict__ ws)
{
    __shared__ __align__(16) float xs[9 * DIN * CIN];   // 9 rows of [w=24][ci=64]
    __shared__ float gsum[NGRP], gsq[NGRP];

    const int bid = blockIdx.x;
    const int n   = bid / (DOUT * DOUT);
    const int rem = bid % (DOUT * DOUT);
    const int d   = rem / DOUT;
    const int h   = rem % DOUT;
    const int tid = threadIdx.x;

    if (tid < NGRP) { gsum[tid] = 0.0f; gsq[tid] = 0.0f; }

    // ---- stage 9 (d-ad, h-ah) rows into LDS, zero-filled outside [0,24) ----
    // each row = 24*64 floats = 384 float4
    for (int idx = tid; idx < 9 * 384; idx += 256) {
        int s = idx / 384;          // s = ad*3 + ah
        int j = idx % 384;          // float4 index within row
        int dd = d - (s / 3);
        int hh = h - (s % 3);
        float4 v = make_float4(0.f, 0.f, 0.f, 0.f);
        if (dd >= 0 && dd < DIN && hh >= 0 && hh < DIN) {
            v = *(const float4*)(x + ((size_t)((n * DIN + dd) * DIN + hh)) * (DIN * CIN) + j * 4);
        }
        *(float4*)(xs + s * (DIN * CIN) + j * 4) = v;
    }
    __syncthreads();

    const int cg = tid & 31;    // co4 group
    const int pg = tid >> 5;    // pixel group

    float acc[4][4];
    #pragma unroll
    for (int p = 0; p < 4; ++p)
        #pragma unroll
        for (int c = 0; c < 4; ++c) acc[p][c] = 0.0f;

    for (int s = 0; s < 9; ++s) {
        const float* xrow = xs + s * (DIN * CIN);
        #pragma unroll
        for (int aw = 0; aw < 3; ++aw) {
            const float* Kt = K + (size_t)((s * 3 + aw) * CIN) * COUT + cg * 4;
            for (int c4 = 0; c4 < 16; ++c4) {
                const float4 wf0 = *(const float4*)(Kt + (c4 * 4 + 0) * COUT);
                const float4 wf1 = *(const float4*)(Kt + (c4 * 4 + 1) * COUT);
                const float4 wf2 = *(const float4*)(Kt + (c4 * 4 + 2) * COUT);
                const float4 wf3 = *(const float4*)(Kt + (c4 * 4 + 3) * COUT);
                #pragma unroll
                for (int p = 0; p < 4; ++p) {
                    const int w    = pg + 8 * p;
                    const int wsrc = w - aw;
                    if (w < DOUT && wsrc >= 0 && wsrc < DIN) {
                        const float4 x4 = *(const float4*)(xrow + wsrc * CIN + c4 * 4);
                        acc[p][0] += x4.x * wf0.x + x4.y * wf1.x + x4.z * wf2.x + x4.w * wf3.x;
                        acc[p][1] += x4.x * wf0.y + x4.y * wf1.y + x4.z * wf2.y + x4.w * wf3.y;
                        acc[p][2] += x4.x * wf0.z + x4.y * wf1.z + x4.z * wf2.z + x4.w * wf3.z;
                        acc[p][3] += x4.x * wf0.w + x4.y * wf1.w + x4.z * wf2.w + x4.w * wf3.w;
                    }
                }
            }
        }
    }

    // ---- ReLU, store, and per-group partial sums ----
    float ls = 0.0f, lsq = 0.0f;
    const size_t rowbase = (size_t)((n * DOUT + d) * DOUT + h) * (DOUT * COUT);
    #pragma unroll
    for (int p = 0; p < 4; ++p) {
        const int w = pg + 8 * p;
        if (w < DOUT) {
            float4 o;
            o.x = fmaxf(acc[p][0], 0.0f);
            o.y = fmaxf(acc[p][1], 0.0f);
            o.z = fmaxf(acc[p][2], 0.0f);
            o.w = fmaxf(acc[p][3], 0.0f);
            *(float4*)(y + rowbase + (size_t)w * COUT + cg * 4) = o;
            ls  += o.x + o.y + o.z + o.w;
            lsq += o.x * o.x + o.y * o.y + o.z * o.z + o.w * o.w;
        }
    }
    const int g = cg >> 2;   // all 4 co of this thread share one group
    atomicAdd(&gsum[g], ls);
    atomicAdd(&gsq[g], lsq);
    __syncthreads();
    if (tid < NGRP) {
        atomicAdd(&ws[(n * NGRP + tid) * 2 + 0], gsum[tid]);
        atomicAdd(&ws[(n * NGRP + tid) * 2 + 1], gsq[tid]);
    }
}

// elementwise normalize: y = (y - mean)*rstd*scale + bias, one float4 per thread
__global__ __launch_bounds__(256) void gn_apply_kernel(
    float* __restrict__ y, const float* __restrict__ ws,
    const float* __restrict__ scale, const float* __restrict__ bias)
{
    const int total4 = N_ * DOUT * DOUT * DOUT * (COUT / 4);   // 8,998,912
    int i = blockIdx.x * 256 + threadIdx.x;
    if (i >= total4) return;

    const int t  = i & 31;        // which float4 within the 128 channels
    const int co = t * 4;
    const int g  = t >> 2;
    const int n  = i / (DOUT * DOUT * DOUT * (COUT / 4));

    const float s  = ws[(n * NGRP + g) * 2 + 0];
    const float sq = ws[(n * NGRP + g) * 2 + 1];
    const float invN = 1.0f / (float)(DOUT * DOUT * DOUT * (COUT / NGRP));
    const float mean = s * invN;
    const float var  = sq * invN - mean * mean;
    const float rstd = rsqrtf(var + EPS);

    float4 v = ((float4*)y)[i];
    const float4 sc = *(const float4*)(scale + co);
    const float4 bi = *(const float4*)(bias + co);
    v.x = (v.x - mean) * rstd * sc.x + bi.x;
    v.y = (v.y - mean) * rstd * sc.y + bi.y;
    v.z = (v.z - mean) * rstd * sc.z + bi.z;
    v.w = (v.w - mean) * rstd * sc.w + bi.w;
    ((float4*)y)[i] = v;
}

extern "C" void kernel_launch(void* const* d_in, const int* in_sizes, int n_in,
                              void* d_out, int out_size, void* d_ws, size_t ws_size,
                              hipStream_t stream) {
    const float* x     = (const float*)d_in[0];
    const float* K     = (const float*)d_in[1];
    const float* scale = (const float*)d_in[2];
    const float* bias  = (const float*)d_in[3];
    float* y  = (float*)d_out;
    float* ws = (float*)d_ws;

    zero_ws_kernel<<<1, 256, 0, stream>>>(ws);
    conv_relu_sum_kernel<<<N_ * DOUT * DOUT, 256, 0, stream>>>(x, K, y, ws);
    const int total4 = N_ * DOUT * DOUT * DOUT * (COUT / 4);
    gn_apply_kernel<<<(total4 + 255) / 256, 256, 0, stream>>>(y, ws, scale, bias);
}

// Round 5
// 536.936 us; speedup vs baseline: 6.4006x; 6.4006x over previous
//
#include <hip/hip_runtime.h>

#define N_    16
#define DIN   24
#define DOUT  26
#define CIN   64
#define COUT  128
#define NGRP  8
#define EPS   1e-5f

// ws layout (bytes) -- total 443,392 B:
//   [0, 1024)      : float stats[N_][NGRP][2] (sum, sumsq) -- zeroed each launch
//   [1024, 443392) : fp16 Kf[54][8][64][8]  (MFMA B-fragment order)
#define STATS_OFF 0
#define KF_OFF    1024

typedef _Float16 half8_t __attribute__((ext_vector_type(8)));
typedef float    f32x4_t __attribute__((ext_vector_type(4)));

// ---- build Kf in MFMA B-fragment order + zero stats ----
// t = ks*512 + nt*64 + lane ; frag element j: ci = (ks&1)*32 + (lane>>4)*8 + j,
// co = nt*16 + (lane&15), tap = ks>>1  (tap = ad*9+ah*3+aw).
__global__ __launch_bounds__(256) void convert_k_kernel(
    const float* __restrict__ K, _Float16* __restrict__ Kf, float* __restrict__ stats)
{
    int t = blockIdx.x * 256 + threadIdx.x;
    if (blockIdx.x == 0 && threadIdx.x < N_ * NGRP * 2) stats[threadIdx.x] = 0.0f;
    if (t >= 54 * 8 * 64) return;
    const int lane = t & 63;
    const int nt   = (t >> 6) & 7;
    const int ks   = t >> 9;
    const int tap  = ks >> 1;
    const int cih  = ks & 1;
    const int q    = lane >> 4;
    const int col  = lane & 15;
    const int ci0  = cih * 32 + q * 8;
    const int co   = nt * 16 + col;
    half8_t h;
    #pragma unroll
    for (int j = 0; j < 8; ++j)
        h[j] = (_Float16)K[(size_t)(tap * CIN + ci0 + j) * COUT + co];
    *(half8_t*)(Kf + (size_t)t * 8) = h;
}

// ---- conv(gather form) + ReLU + group partial sums via MFMA ----
// one block per output row (n,d,h); 4 waves: wv&1 -> M-tile (w 0..15/16..25),
// wv>>1 -> N-half (couts 0..63 / 64..127), 4 frags of 16 couts each.
__global__ __launch_bounds__(256, 4) void conv_mfma_kernel(
    const float* __restrict__ x, const _Float16* __restrict__ Kf,
    float* __restrict__ y, float* __restrict__ stats)
{
    // 9 rows x 28 w-slots (2 pad each side) x 72 fp16 (64 ci + 8 tail pad)
    __shared__ __align__(16) _Float16 xs[9 * 28 * 72];   // 36,288 B
    __shared__ float gsum[NGRP], gsq[NGRP];

    const int bid = blockIdx.x;
    const int n   = bid / (DOUT * DOUT);
    const int rem = bid % (DOUT * DOUT);
    const int d   = rem / DOUT;
    const int h   = rem % DOUT;
    const int tid = threadIdx.x;

    if (tid < NGRP) { gsum[tid] = 0.0f; gsq[tid] = 0.0f; }

    // Stage ALL 9*28*9 = 2268 16-B chunks: loads where in-range, zeros elsewhere.
    // (Bug in r2-r4: pad zeroing used `if (tid < 324)` with 256 threads -> chunks
    //  256..323 kept stale LDS garbage. This loop covers every chunk by design.)
    for (int c = tid; c < 2268; c += 256) {
        const int s    = c / 252;        // staging row: s = ad*3 + ah
        const int rr   = c % 252;
        const int slot = rr / 9;         // 0..27 ; source w = slot - 2
        const int ch   = rr % 9;         // 16-B chunk within slot (ch<8 = real ci)
        const int dd = d - s / 3;
        const int hh = h - s % 3;
        const int w  = slot - 2;
        half8_t v = {};
        if (ch < 8 && dd >= 0 && dd < DIN && hh >= 0 && hh < DIN && w >= 0 && w < DIN) {
            const float* src = x + ((size_t)(((n * DIN + dd) * DIN + hh) * DIN + w)) * CIN + ch * 8;
            const float4 a = *(const float4*)(src);
            const float4 b = *(const float4*)(src + 4);
            v[0] = (_Float16)a.x; v[1] = (_Float16)a.y; v[2] = (_Float16)a.z; v[3] = (_Float16)a.w;
            v[4] = (_Float16)b.x; v[5] = (_Float16)b.y; v[6] = (_Float16)b.z; v[7] = (_Float16)b.w;
        }
        *(half8_t*)(xs + s * 2016 + slot * 72 + ch * 8) = v;
    }
    __syncthreads();

    const int lane = tid & 63;
    const int wv   = tid >> 6;
    const int M0   = (wv & 1) * 16;
    const int wnt  = wv >> 1;
    const int q    = lane >> 4;
    const int col  = lane & 15;

    // A-frag slot per aw (clamp: M rows >= 26 land in zeroed pad slot 27)
    const int slotb = M0 + col + 2;
    int aoff[3];
    #pragma unroll
    for (int aw = 0; aw < 3; ++aw) {
        int sl = slotb - aw; if (sl > 27) sl = 27;
        aoff[aw] = sl * 72 + q * 8;
    }

    f32x4_t acc[4];
    #pragma unroll
    for (int f = 0; f < 4; ++f) acc[f] = f32x4_t{0.f, 0.f, 0.f, 0.f};

    const _Float16* Kfl = Kf + lane * 8;
    for (int r = 0; r < 9; ++r) {
        const int rbase = r * 2016;
        #pragma unroll
        for (int aw = 0; aw < 3; ++aw) {
            const int ks0 = (r * 3 + aw) * 2;
            #pragma unroll
            for (int cih = 0; cih < 2; ++cih) {
                half8_t a = *(const half8_t*)(xs + rbase + aoff[aw] + cih * 32);
                #pragma unroll
                for (int f = 0; f < 4; ++f) {
                    half8_t b = *(const half8_t*)(Kfl + (size_t)(((ks0 + cih) * 8) + wnt * 4 + f) * 512);
                    acc[f] = __builtin_amdgcn_mfma_f32_16x16x32_f16(a, b, acc[f], 0, 0, 0);
                }
            }
        }
    }

    // epilogue: ReLU, store, per-group sums. C/D: col=lane&15 (cout), row=q*4+reg (w)
    const size_t rowbase = ((size_t)((n * DOUT + d) * DOUT + h)) * (DOUT * COUT);
    #pragma unroll
    for (int f = 0; f < 4; ++f) {
        const int cout = (wnt * 4 + f) * 16 + col;
        float ls = 0.f, lsq = 0.f;
        #pragma unroll
        for (int reg = 0; reg < 4; ++reg) {
            const int wout = M0 + q * 4 + reg;
            float v = fmaxf(acc[f][reg], 0.0f);
            if (wout < DOUT) {
                y[rowbase + (size_t)wout * COUT + cout] = v;
                ls += v; lsq += v * v;
            }
        }
        #pragma unroll
        for (int off = 1; off < 64; off <<= 1) {
            ls  += __shfl_xor(ls, off);
            lsq += __shfl_xor(lsq, off);
        }
        if (lane == 0) {
            atomicAdd(&gsum[wnt * 4 + f], ls);
            atomicAdd(&gsq[wnt * 4 + f], lsq);
        }
    }
    __syncthreads();
    if (tid < NGRP) {
        atomicAdd(&stats[(n * NGRP + tid) * 2 + 0], gsum[tid]);
        atomicAdd(&stats[(n * NGRP + tid) * 2 + 1], gsq[tid]);
    }
}

// ---- elementwise normalize ----
__global__ __launch_bounds__(256) void gn_apply_kernel(
    float* __restrict__ y, const float* __restrict__ stats,
    const float* __restrict__ scale, const float* __restrict__ bias)
{
    const int total4 = N_ * DOUT * DOUT * DOUT * (COUT / 4);
    int i = blockIdx.x * 256 + threadIdx.x;
    if (i >= total4) return;

    const int t  = i & 31;
    const int co = t * 4;
    const int g  = t >> 2;
    const int n  = i / (DOUT * DOUT * DOUT * (COUT / 4));

    const float s  = stats[(n * NGRP + g) * 2 + 0];
    const float sq = stats[(n * NGRP + g) * 2 + 1];
    const float invN = 1.0f / (float)(DOUT * DOUT * DOUT * (COUT / NGRP));
    const float mean = s * invN;
    const float var  = sq * invN - mean * mean;
    const float rstd = rsqrtf(var + EPS);

    float4 v = ((float4*)y)[i];
    const float4 sc = *(const float4*)(scale + co);
    const float4 bi = *(const float4*)(bias + co);
    v.x = (v.x - mean) * rstd * sc.x + bi.x;
    v.y = (v.y - mean) * rstd * sc.y + bi.y;
    v.z = (v.z - mean) * rstd * sc.z + bi.z;
    v.w = (v.w - mean) * rstd * sc.w + bi.w;
    ((float4*)y)[i] = v;
}

extern "C" void kernel_launch(void* const* d_in, const int* in_sizes, int n_in,
                              void* d_out, int out_size, void* d_ws, size_t ws_size,
                              hipStream_t stream) {
    const float* x     = (const float*)d_in[0];
    const float* K     = (const float*)d_in[1];
    const float* scale = (const float*)d_in[2];
    const float* bias  = (const float*)d_in[3];
    float* y = (float*)d_out;

    float*    stats = (float*)((char*)d_ws + STATS_OFF);
    _Float16* Kf    = (_Float16*)((char*)d_ws + KF_OFF);

    convert_k_kernel<<<108, 256, 0, stream>>>(K, Kf, stats);
    conv_mfma_kernel<<<N_ * DOUT * DOUT, 256, 0, stream>>>(x, Kf, y, stats);
    const int total4 = N_ * DOUT * DOUT * DOUT * (COUT / 4);
    gn_apply_kernel<<<(total4 + 255) / 256, 256, 0, stream>>>(y, stats, scale, bias);
}

// Round 6
// 396.332 us; speedup vs baseline: 8.6713x; 1.3548x over previous
//
#include <hip/hip_runtime.h>

#define N_    16
#define DIN   24
#define DOUT  26
#define CIN   64
#define COUT  128
#define NGRP  8
#define EPS   1e-5f

// ws layout (bytes) -- total 443,392 B:
//   [0, 1024)      : float stats[N_][NGRP][2] (sum, sumsq) -- zeroed each launch
//   [1024, 443392) : fp16 Kf[54][8][64][8]  (MFMA B-fragment order)
#define STATS_OFF 0
#define KF_OFF    1024

typedef _Float16 half8_t __attribute__((ext_vector_type(8)));
typedef float    f32x4_t __attribute__((ext_vector_type(4)));

// ---- build Kf in MFMA B-fragment order + zero stats ----
// t = ks*512 + nt*64 + lane ; element j: ci = (ks&1)*32 + (lane>>4)*8 + j,
// co = nt*16 + (lane&15), tap = ks>>1 (tap = ad*9+ah*3+aw).
__global__ __launch_bounds__(256) void convert_k_kernel(
    const float* __restrict__ K, _Float16* __restrict__ Kf, float* __restrict__ stats)
{
    int t = blockIdx.x * 256 + threadIdx.x;
    if (blockIdx.x == 0 && threadIdx.x < N_ * NGRP * 2) stats[threadIdx.x] = 0.0f;
    if (t >= 54 * 8 * 64) return;
    const int lane = t & 63;
    const int nt   = (t >> 6) & 7;
    const int ks   = t >> 9;
    const int tap  = ks >> 1;
    const int cih  = ks & 1;
    const int q    = lane >> 4;
    const int col  = lane & 15;
    const int ci0  = cih * 32 + q * 8;
    const int co   = nt * 16 + col;
    half8_t h;
    #pragma unroll
    for (int j = 0; j < 8; ++j)
        h[j] = (_Float16)K[(size_t)(tap * CIN + ci0 + j) * COUT + co];
    *(half8_t*)(Kf + (size_t)t * 8) = h;
}

// ---- conv(gather) + ReLU + group sums. Block = (n, d, h-pair); 4 waves.
// Each wave: ALL 4 M-tiles (2 h-rows x 32 w) x 2 N-frags (couts wv*32..wv*32+31).
// B regs reused across 4 M-tiles -> L2 B traffic / 4 vs round 5.
__global__ __launch_bounds__(256, 3) void conv_mfma_kernel(
    const float* __restrict__ x, const _Float16* __restrict__ Kf,
    float* __restrict__ y, float* __restrict__ stats)
{
    // 12 staging rows: (ad 0..2) x (hsub 0..3, hh = hb+hsub-2); 28 w-slots
    // (2 pad each side) x 72 fp16 (64 ci + 8 tail pad).
    __shared__ __align__(16) _Float16 xs[12 * 28 * 72];   // 48,384 B
    __shared__ float gsum[NGRP], gsq[NGRP];

    const int bid = blockIdx.x;
    const int n   = bid / (DOUT * 13);
    const int rem = bid % (DOUT * 13);
    const int d   = rem / 13;
    const int hb  = (rem % 13) * 2;
    const int tid = threadIdx.x;

    if (tid < NGRP) { gsum[tid] = 0.0f; gsq[tid] = 0.0f; }

    // Stage ALL 12*28*9 = 3024 16-B chunks (zeros where out of range).
    for (int c = tid; c < 3024; c += 256) {
        const int s    = c / 252;        // s = ad*4 + hsub
        const int rr   = c % 252;
        const int slot = rr / 9;         // source w = slot - 2
        const int ch   = rr % 9;         // ch<8 = real ci chunk, ch==8 = tail pad
        const int dd = d - (s >> 2);
        const int hh = hb + (s & 3) - 2;
        const int w  = slot - 2;
        half8_t v = {};
        if (ch < 8 && dd >= 0 && dd < DIN && hh >= 0 && hh < DIN && w >= 0 && w < DIN) {
            const float* src = x + ((size_t)(((n * DIN + dd) * DIN + hh) * DIN + w)) * CIN + ch * 8;
            const float4 a = *(const float4*)(src);
            const float4 b = *(const float4*)(src + 4);
            v[0] = (_Float16)a.x; v[1] = (_Float16)a.y; v[2] = (_Float16)a.z; v[3] = (_Float16)a.w;
            v[4] = (_Float16)b.x; v[5] = (_Float16)b.y; v[6] = (_Float16)b.z; v[7] = (_Float16)b.w;
        }
        *(half8_t*)(xs + s * 2016 + slot * 72 + ch * 8) = v;
    }
    __syncthreads();

    const int lane = tid & 63;
    const int wv   = tid >> 6;          // wave owns couts [wv*32, wv*32+32)
    const int q    = lane >> 4;
    const int col  = lane & 15;

    f32x4_t acc[4][2];
    #pragma unroll
    for (int mt = 0; mt < 4; ++mt)
        #pragma unroll
        for (int fi = 0; fi < 2; ++fi) acc[mt][fi] = f32x4_t{0.f, 0.f, 0.f, 0.f};

    const _Float16* Kfl = Kf + lane * 8;
    for (int r = 0; r < 9; ++r) {        // r = ad*3 + ah
        const int ad = r / 3, ah = r % 3;
        // staging row base per hq: s = ad*4 + (hq - ah + 2)
        int sbase[2];
        sbase[0] = (ad * 4 + (2 - ah)) * 2016;
        sbase[1] = (ad * 4 + (3 - ah)) * 2016;
        #pragma unroll
        for (int aw = 0; aw < 3; ++aw) {
            int aoff[4];
            #pragma unroll
            for (int mt = 0; mt < 4; ++mt) {
                int sl = (mt & 1) * 16 + col - aw + 2;
                if (sl > 27) sl = 27;                 // zeroed pad slot
                aoff[mt] = sbase[mt >> 1] + sl * 72 + q * 8;
            }
            const int ks0 = (r * 3 + aw) * 2;
            #pragma unroll
            for (int cih = 0; cih < 2; ++cih) {
                const _Float16* Bp = Kfl + (size_t)(((ks0 + cih) * 8) + wv * 2) * 512;
                half8_t b0 = *(const half8_t*)(Bp);
                half8_t b1 = *(const half8_t*)(Bp + 512);
                #pragma unroll
                for (int mt = 0; mt < 4; ++mt) {
                    half8_t a = *(const half8_t*)(xs + aoff[mt] + cih * 32);
                    acc[mt][0] = __builtin_amdgcn_mfma_f32_16x16x32_f16(a, b0, acc[mt][0], 0, 0, 0);
                    acc[mt][1] = __builtin_amdgcn_mfma_f32_16x16x32_f16(a, b1, acc[mt][1], 0, 0, 0);
                }
            }
        }
    }

    // epilogue: ReLU, store, per-group sums. C/D: col=cout-in-frag, row=q*4+reg.
    #pragma unroll
    for (int fi = 0; fi < 2; ++fi) {
        const int g    = wv * 2 + fi;        // frag == one GN group (16 couts)
        const int cout = g * 16 + col;
        float ls = 0.f, lsq = 0.f;
        #pragma unroll
        for (int mt = 0; mt < 4; ++mt) {
            const int hq = mt >> 1;
            const size_t rowbase =
                (((size_t)(n * DOUT + d)) * DOUT + (hb + hq)) * (DOUT * COUT);
            #pragma unroll
            for (int reg = 0; reg < 4; ++reg) {
                const int wout = (mt & 1) * 16 + q * 4 + reg;
                float v = fmaxf(acc[mt][fi][reg], 0.0f);
                if (wout < DOUT) {
                    y[rowbase + (size_t)wout * COUT + cout] = v;
                    ls += v; lsq += v * v;
                }
            }
        }
        #pragma unroll
        for (int off = 1; off < 64; off <<= 1) {
            ls  += __shfl_xor(ls, off);
            lsq += __shfl_xor(lsq, off);
        }
        if (lane == 0) {
            atomicAdd(&gsum[g], ls);
            atomicAdd(&gsq[g], lsq);
        }
    }
    __syncthreads();
    if (tid < NGRP) {
        atomicAdd(&stats[(n * NGRP + tid) * 2 + 0], gsum[tid]);
        atomicAdd(&stats[(n * NGRP + tid) * 2 + 1], gsq[tid]);
    }
}

// ---- elementwise normalize ----
__global__ __launch_bounds__(256) void gn_apply_kernel(
    float* __restrict__ y, const float* __restrict__ stats,
    const float* __restrict__ scale, const float* __restrict__ bias)
{
    const int total4 = N_ * DOUT * DOUT * DOUT * (COUT / 4);
    int i = blockIdx.x * 256 + threadIdx.x;
    if (i >= total4) return;

    const int t  = i & 31;
    const int co = t * 4;
    const int g  = t >> 2;
    const int n  = i / (DOUT * DOUT * DOUT * (COUT / 4));

    const float s  = stats[(n * NGRP + g) * 2 + 0];
    const float sq = stats[(n * NGRP + g) * 2 + 1];
    const float invN = 1.0f / (float)(DOUT * DOUT * DOUT * (COUT / NGRP));
    const float mean = s * invN;
    const float var  = sq * invN - mean * mean;
    const float rstd = rsqrtf(var + EPS);

    float4 v = ((float4*)y)[i];
    const float4 sc = *(const float4*)(scale + co);
    const float4 bi = *(const float4*)(bias + co);
    v.x = (v.x - mean) * rstd * sc.x + bi.x;
    v.y = (v.y - mean) * rstd * sc.y + bi.y;
    v.z = (v.z - mean) * rstd * sc.z + bi.z;
    v.w = (v.w - mean) * rstd * sc.w + bi.w;
    ((float4*)y)[i] = v;
}

extern "C" void kernel_launch(void* const* d_in, const int* in_sizes, int n_in,
                              void* d_out, int out_size, void* d_ws, size_t ws_size,
                              hipStream_t stream) {
    const float* x     = (const float*)d_in[0];
    const float* K     = (const float*)d_in[1];
    const float* scale = (const float*)d_in[2];
    const float* bias  = (const float*)d_in[3];
    float* y = (float*)d_out;

    float*    stats = (float*)((char*)d_ws + STATS_OFF);
    _Float16* Kf    = (_Float16*)((char*)d_ws + KF_OFF);

    convert_k_kernel<<<108, 256, 0, stream>>>(K, Kf, stats);
    conv_mfma_kernel<<<N_ * DOUT * 13, 256, 0, stream>>>(x, Kf, y, stats);
    const int total4 = N_ * DOUT * DOUT * DOUT * (COUT / 4);
    gn_apply_kernel<<<(total4 + 255) / 256, 256, 0, stream>>>(y, stats, scale, bias);
}

// Round 7
// 377.629 us; speedup vs baseline: 9.1008x; 1.0495x over previous
//
#include <hip/hip_runtime.h>

#define N_    16
#define DIN   24
#define DOUT  26
#define CIN   64
#define COUT  128
#define NGRP  8
#define EPS   1e-5f

// ws layout (bytes) -- total 443,392 B (proven OK in rounds 5/6):
//   [0, 1024)      : float stats[N_][NGRP][2] (sum, sumsq) -- zeroed each launch
//   [1024, 443392) : fp16 Kf[27][4][4][64][8]  (32x32 MFMA B-fragment order)
#define STATS_OFF 0
#define KF_OFF    1024

typedef _Float16 half8_t  __attribute__((ext_vector_type(8)));
typedef float    f32x16_t __attribute__((ext_vector_type(16)));

// ---- build Kf in 32x32x16 B-fragment order + zero stats ----
// frag (tap, ck, nf): element j of lane: k(ci) = ck*16 + (lane>>5)*8 + j,
// n(co) = nf*32 + (lane&31).   t = ((tap*4 + ck)*4 + nf)*64 + lane.
__global__ __launch_bounds__(256) void convert_k_kernel(
    const float* __restrict__ K, _Float16* __restrict__ Kf, float* __restrict__ stats)
{
    int t = blockIdx.x * 256 + threadIdx.x;          // 27 blocks... 108 blocks of 256 -> 27648
    if (blockIdx.x == 0 && threadIdx.x < N_ * NGRP * 2) stats[threadIdx.x] = 0.0f;
    if (t >= 27 * 4 * 4 * 64) return;
    const int lane = t & 63;
    const int nf   = (t >> 6) & 3;
    const int ck   = (t >> 8) & 3;
    const int tap  = t >> 10;                        // 0..26 = ad*9+ah*3+aw
    const int ci0  = ck * 16 + (lane >> 5) * 8;
    const int co   = nf * 32 + (lane & 31);
    half8_t h;
    #pragma unroll
    for (int j = 0; j < 8; ++j)
        h[j] = (_Float16)K[(size_t)(tap * CIN + ci0 + j) * COUT + co];
    *(half8_t*)(Kf + (size_t)t * 8) = h;
}

// ---- conv(gather) + ReLU + group sums, 32x32x16 MFMA ----
// Block = (n, d, h-quad hb=4*q). M-tiles = 4 h-rows x (w 0..31, rows>=26 masked).
// 4 waves: (wv&1) -> h-pair, (wv>>1) -> cout-pair (2 N-frags of 32).
// Per k16-step: 2 A ds_read_b128 + 2 B L2 loads -> 4 MFMA (A reused x2, B x2).
__global__ __launch_bounds__(256, 2) void conv_mfma_kernel(
    const float* __restrict__ x, const _Float16* __restrict__ Kf,
    float* __restrict__ y, float* __restrict__ stats)
{
    // 18 staging rows: (ad 0..2) x (hs 0..5, hh = hb+hs-2); 28 w-slots
    // (2 pad each side) x 72 fp16 (64 ci + 8 tail pad).
    __shared__ __align__(16) _Float16 xs[18 * 28 * 72];   // 72,576 B
    __shared__ float gsum[NGRP], gsq[NGRP];

    const int bid = blockIdx.x;
    const int n   = bid / (DOUT * 7);
    const int rem = bid % (DOUT * 7);
    const int d   = rem / 7;
    const int hb  = (rem % 7) * 4;
    const int tid = threadIdx.x;

    if (tid < NGRP) { gsum[tid] = 0.0f; gsq[tid] = 0.0f; }

    // Stage ALL 18*28*9 = 4536 16-B chunks (zeros wherever out of range).
    for (int c = tid; c < 4536; c += 256) {
        const int s    = c / 252;        // s = ad*6 + hs
        const int rr   = c % 252;
        const int slot = rr / 9;         // source w = slot - 2
        const int ch   = rr % 9;         // ch<8 = real ci chunk, ch==8 = tail pad
        const int dd = d - s / 6;
        const int hh = hb + (s % 6) - 2;
        const int w  = slot - 2;
        half8_t v = {};
        if (ch < 8 && dd >= 0 && dd < DIN && hh >= 0 && hh < DIN && w >= 0 && w < DIN) {
            const float* src = x + ((size_t)(((n * DIN + dd) * DIN + hh) * DIN + w)) * CIN + ch * 8;
            const float4 a = *(const float4*)(src);
            const float4 b = *(const float4*)(src + 4);
            v[0] = (_Float16)a.x; v[1] = (_Float16)a.y; v[2] = (_Float16)a.z; v[3] = (_Float16)a.w;
            v[4] = (_Float16)b.x; v[5] = (_Float16)b.y; v[6] = (_Float16)b.z; v[7] = (_Float16)b.w;
        }
        *(half8_t*)(xs + s * 2016 + slot * 72 + ch * 8) = v;
    }
    __syncthreads();

    const int lane = tid & 63;
    const int wv   = tid >> 6;
    const int hp   = wv & 1;            // h-pair: rows hb+2*hp, hb+2*hp+1
    const int nfp  = wv >> 1;           // cout frags nfp*2, nfp*2+1 (each 32 couts)
    const int col  = lane & 31;         // A: m (=w) ; B/C/D: n (cout within frag)
    const int hi   = lane >> 5;         // k-half selector

    // A slot for each aw: slot = col - aw + 2 (clamped into zeroed pad slot 27)
    int aofs[3];
    #pragma unroll
    for (int aw = 0; aw < 3; ++aw) {
        int sl = col - aw + 2; if (sl > 27) sl = 27;
        aofs[aw] = sl * 72 + hi * 8;
    }

    f32x16_t acc[2][2];
    #pragma unroll
    for (int mt = 0; mt < 2; ++mt)
        #pragma unroll
        for (int fi = 0; fi < 2; ++fi) acc[mt][fi] = (f32x16_t)(0.0f);

    const _Float16* Kfl = Kf + (size_t)lane * 8;
    for (int ad = 0; ad < 3; ++ad) {
        for (int ah = 0; ah < 3; ++ah) {
            // staging rows for this wave's two h-rows
            const int s0 = (ad * 6 + (2 * hp + 0) - ah + 2) * 2016;
            const int s1 = s0 + 2016;
            const int tap = (ad * 3 + ah) * 3;
            #pragma unroll
            for (int aw = 0; aw < 3; ++aw) {
                const _Float16* Bt = Kfl + (size_t)(((tap + aw) * 4) * 4 + nfp * 2) * 512;
                #pragma unroll
                for (int ck = 0; ck < 4; ++ck) {
                    half8_t a0 = *(const half8_t*)(xs + s0 + aofs[aw] + ck * 16);
                    half8_t a1 = *(const half8_t*)(xs + s1 + aofs[aw] + ck * 16);
                    half8_t b0 = *(const half8_t*)(Bt + (size_t)(ck * 4) * 512);
                    half8_t b1 = *(const half8_t*)(Bt + (size_t)(ck * 4 + 1) * 512);
                    acc[0][0] = __builtin_amdgcn_mfma_f32_32x32x16_f16(a0, b0, acc[0][0], 0, 0, 0);
                    acc[0][1] = __builtin_amdgcn_mfma_f32_32x32x16_f16(a0, b1, acc[0][1], 0, 0, 0);
                    acc[1][0] = __builtin_amdgcn_mfma_f32_32x32x16_f16(a1, b0, acc[1][0], 0, 0, 0);
                    acc[1][1] = __builtin_amdgcn_mfma_f32_32x32x16_f16(a1, b1, acc[1][1], 0, 0, 0);
                }
            }
        }
    }

    // epilogue. C/D (HW-verified): col(cout)=lane&31, row(w)=(reg&3)+8*(reg>>2)+4*hi
    #pragma unroll
    for (int mt = 0; mt < 2; ++mt) {
        const int hrow = hb + 2 * hp + mt;
        if (hrow >= DOUT) continue;
        const size_t rowbase = (((size_t)(n * DOUT + d)) * DOUT + hrow) * (DOUT * COUT);
        #pragma unroll
        for (int fi = 0; fi < 2; ++fi) {
            const int fr   = nfp * 2 + fi;
            const int cout = fr * 32 + col;
            float ls = 0.f, lsq = 0.f;
            #pragma unroll
            for (int reg = 0; reg < 16; ++reg) {
                const int wout = (reg & 3) + 8 * (reg >> 2) + 4 * hi;
                float v = fmaxf(acc[mt][fi][reg], 0.0f);
                if (wout < DOUT) {
                    y[rowbase + (size_t)wout * COUT + cout] = v;
                    ls += v; lsq += v * v;
                }
            }
            // reduce within the 32-lane cohort sharing one GN group:
            // cohort = lanes with same (col>>4); spanned by xor {1,2,4,8,32}
            #pragma unroll
            for (int off = 1; off < 16; off <<= 1) {
                ls  += __shfl_xor(ls, off);
                lsq += __shfl_xor(lsq, off);
            }
            ls  += __shfl_xor(ls, 32);
            lsq += __shfl_xor(lsq, 32);
            if (lane == 0 || lane == 16) {
                const int g = fr * 2 + (col >> 4);   // 8 groups of 16 couts
                atomicAdd(&gsum[g], ls);
                atomicAdd(&gsq[g], lsq);
            }
        }
    }
    __syncthreads();
    if (tid < NGRP) {
        atomicAdd(&stats[(n * NGRP + tid) * 2 + 0], gsum[tid]);
        atomicAdd(&stats[(n * NGRP + tid) * 2 + 1], gsq[tid]);
    }
}

// ---- elementwise normalize ----
__global__ __launch_bounds__(256) void gn_apply_kernel(
    float* __restrict__ y, const float* __restrict__ stats,
    const float* __restrict__ scale, const float* __restrict__ bias)
{
    const int total4 = N_ * DOUT * DOUT * DOUT * (COUT / 4);
    int i = blockIdx.x * 256 + threadIdx.x;
    if (i >= total4) return;

    const int t  = i & 31;
    const int co = t * 4;
    const int g  = t >> 2;
    const int n  = i / (DOUT * DOUT * DOUT * (COUT / 4));

    const float s  = stats[(n * NGRP + g) * 2 + 0];
    const float sq = stats[(n * NGRP + g) * 2 + 1];
    const float invN = 1.0f / (float)(DOUT * DOUT * DOUT * (COUT / NGRP));
    const float mean = s * invN;
    const float var  = sq * invN - mean * mean;
    const float rstd = rsqrtf(var + EPS);

    float4 v = ((float4*)y)[i];
    const float4 sc = *(const float4*)(scale + co);
    const float4 bi = *(const float4*)(bias + co);
    v.x = (v.x - mean) * rstd * sc.x + bi.x;
    v.y = (v.y - mean) * rstd * sc.y + bi.y;
    v.z = (v.z - mean) * rstd * sc.z + bi.z;
    v.w = (v.w - mean) * rstd * sc.w + bi.w;
    ((float4*)y)[i] = v;
}

extern "C" void kernel_launch(void* const* d_in, const int* in_sizes, int n_in,
                              void* d_out, int out_size, void* d_ws, size_t ws_size,
                              hipStream_t stream) {
    const float* x     = (const float*)d_in[0];
    const float* K     = (const float*)d_in[1];
    const float* scale = (const float*)d_in[2];
    const float* bias  = (const float*)d_in[3];
    float* y = (float*)d_out;

    float*    stats = (float*)((char*)d_ws + STATS_OFF);
    _Float16* Kf    = (_Float16*)((char*)d_ws + KF_OFF);

    convert_k_kernel<<<108, 256, 0, stream>>>(K, Kf, stats);
    conv_mfma_kernel<<<N_ * DOUT * 7, 256, 0, stream>>>(x, Kf, y, stats);
    const int total4 = N_ * DOUT * DOUT * DOUT * (COUT / 4);
    gn_apply_kernel<<<(total4 + 255) / 256, 256, 0, stream>>>(y, stats, scale, bias);
}

// Round 8
// 358.176 us; speedup vs baseline: 9.5951x; 1.0543x over previous
//
#include <hip/hip_runtime.h>

#define N_    16
#define DIN   24
#define DOUT  26
#define CIN   64
#define COUT  128
#define NGRP  8
#define EPS   1e-5f

// ws layout (bytes) -- total 443,392 B (proven OK in rounds 5-7):
//   [0, 1024)      : float stats[N_][NGRP][2] (sum, sumsq) -- zeroed each launch
//   [1024, 443392) : fp16 Kf[27][4][4][64][8]  (32x32 MFMA B-fragment order)
#define STATS_OFF 0
#define KF_OFF    1024

typedef _Float16 half8_t  __attribute__((ext_vector_type(8)));
typedef float    f32x16_t __attribute__((ext_vector_type(16)));

// ---- build Kf in 32x32x16 B-fragment order + zero stats ----
// frag (tap, ckg, nf): element j of lane: k(ci) = ckg*16 + (lane>>5)*8 + j,
// n(co) = nf*32 + (lane&31).   t = ((tap*4 + ckg)*4 + nf)*64 + lane.
__global__ __launch_bounds__(256) void convert_k_kernel(
    const float* __restrict__ K, _Float16* __restrict__ Kf, float* __restrict__ stats)
{
    int t = blockIdx.x * 256 + threadIdx.x;
    if (blockIdx.x == 0 && threadIdx.x < N_ * NGRP * 2) stats[threadIdx.x] = 0.0f;
    if (t >= 27 * 4 * 4 * 64) return;
    const int lane = t & 63;
    const int nf   = (t >> 6) & 3;
    const int ckg  = (t >> 8) & 3;
    const int tap  = t >> 10;                        // 0..26 = ad*9+ah*3+aw
    const int ci0  = ckg * 16 + (lane >> 5) * 8;
    const int co   = nf * 32 + (lane & 31);
    half8_t h;
    #pragma unroll
    for (int j = 0; j < 8; ++j)
        h[j] = (_Float16)K[(size_t)(tap * CIN + ci0 + j) * COUT + co];
    *(half8_t*)(Kf + (size_t)t * 8) = h;
}

// ---- conv(gather) + ReLU + group sums, 32x32x16 MFMA, ci-split staging ----
// Block = (n, d, h-quad). 4 waves: (wv&1)->h-pair, (wv>>1)->cout-pair.
// Phase ph in {0,1}: stage ci ph*32..ph*32+31 for all 18 (ad,hh) rows, barrier,
// run all 27 taps x 2 k16-steps; acc persists across phases.
// LDS 39.4 KB -> 4 blocks/CU (vs 72.6 KB / 2 blocks in round 7).
__global__ __launch_bounds__(256, 4) void conv_mfma_kernel(
    const float* __restrict__ x, const _Float16* __restrict__ Kf,
    float* __restrict__ y, float* __restrict__ stats)
{
    // 18 rows (ad 0..2 x hs 0..5, hh=hb+hs-2); 28 w-slots; slot stride 40 half
    // (32 ci data + 8 pad halves never read; 80 B keeps b128 16-B aligned).
    __shared__ __align__(16) _Float16 xs[18 * 28 * 40];   // 40,320 B
    __shared__ float gsum[NGRP], gsq[NGRP];

    const int bid = blockIdx.x;
    const int n   = bid / (DOUT * 7);
    const int rem = bid % (DOUT * 7);
    const int d   = rem / 7;
    const int hb  = (rem % 7) * 4;
    const int tid = threadIdx.x;

    if (tid < NGRP) { gsum[tid] = 0.0f; gsq[tid] = 0.0f; }

    const int lane = tid & 63;
    const int wv   = tid >> 6;
    const int hp   = wv & 1;            // h-pair: rows hb+2*hp, hb+2*hp+1
    const int nfp  = wv >> 1;           // cout frags nfp*2, nfp*2+1 (32 couts each)
    const int col  = lane & 31;         // A: m(=w) ; B/C/D: n(cout in frag)
    const int hi   = lane >> 5;         // k-half selector

    int aofs[3];
    #pragma unroll
    for (int aw = 0; aw < 3; ++aw) {
        int sl = col - aw + 2; if (sl > 27) sl = 27;   // slot 27 always zero-staged
        aofs[aw] = sl * 40 + hi * 8;
    }

    f32x16_t acc[2][2];
    #pragma unroll
    for (int mt = 0; mt < 2; ++mt)
        #pragma unroll
        for (int fi = 0; fi < 2; ++fi) acc[mt][fi] = (f32x16_t)(0.0f);

    const _Float16* Kfl = Kf + (size_t)lane * 8;

    for (int ph = 0; ph < 2; ++ph) {
        // ---- stage this phase's 32 ci: 18*28*4 = 2016 16-B chunks ----
        for (int c = tid; c < 2016; c += 256) {
            const int s    = c / 112;        // s = ad*6 + hs
            const int rr   = c % 112;
            const int slot = rr >> 2;        // source w = slot - 2
            const int ch   = rr & 3;
            const int dd = d - s / 6;
            const int hh = hb + (s % 6) - 2;
            const int w  = slot - 2;
            half8_t v = {};
            if (dd >= 0 && dd < DIN && hh >= 0 && hh < DIN && w >= 0 && w < DIN) {
                const float* src = x + ((size_t)(((n * DIN + dd) * DIN + hh) * DIN + w)) * CIN
                                     + ph * 32 + ch * 8;
                const float4 a = *(const float4*)(src);
                const float4 b = *(const float4*)(src + 4);
                v[0] = (_Float16)a.x; v[1] = (_Float16)a.y; v[2] = (_Float16)a.z; v[3] = (_Float16)a.w;
                v[4] = (_Float16)b.x; v[5] = (_Float16)b.y; v[6] = (_Float16)b.z; v[7] = (_Float16)b.w;
            }
            *(half8_t*)(xs + s * 1120 + slot * 40 + ch * 8) = v;
        }
        __syncthreads();

        // ---- all 27 taps, 2 k16-steps within this ci-half ----
        for (int ad = 0; ad < 3; ++ad) {
            for (int ah = 0; ah < 3; ++ah) {
                const int s0  = (ad * 6 + 2 * hp - ah + 2) * 1120;
                const int s1  = s0 + 1120;
                const int tap = (ad * 3 + ah) * 3;
                #pragma unroll
                for (int aw = 0; aw < 3; ++aw) {
                    const _Float16* Bt = Kfl + (size_t)(((tap + aw) * 4 + ph * 2) * 4 + nfp * 2) * 512;
                    #pragma unroll
                    for (int ck = 0; ck < 2; ++ck) {
                        half8_t a0 = *(const half8_t*)(xs + s0 + aofs[aw] + ck * 16);
                        half8_t a1 = *(const half8_t*)(xs + s1 + aofs[aw] + ck * 16);
                        half8_t b0 = *(const half8_t*)(Bt + (size_t)(ck * 4) * 512);
                        half8_t b1 = *(const half8_t*)(Bt + (size_t)(ck * 4 + 1) * 512);
                        acc[0][0] = __builtin_amdgcn_mfma_f32_32x32x16_f16(a0, b0, acc[0][0], 0, 0, 0);
                        acc[0][1] = __builtin_amdgcn_mfma_f32_32x32x16_f16(a0, b1, acc[0][1], 0, 0, 0);
                        acc[1][0] = __builtin_amdgcn_mfma_f32_32x32x16_f16(a1, b0, acc[1][0], 0, 0, 0);
                        acc[1][1] = __builtin_amdgcn_mfma_f32_32x32x16_f16(a1, b1, acc[1][1], 0, 0, 0);
                    }
                }
            }
        }
        if (ph == 0) __syncthreads();   // protect LDS before re-staging
    }

    // epilogue. C/D (HW-verified): col(cout)=lane&31, row(w)=(reg&3)+8*(reg>>2)+4*hi
    #pragma unroll
    for (int mt = 0; mt < 2; ++mt) {
        const int hrow = hb + 2 * hp + mt;
        if (hrow >= DOUT) continue;
        const size_t rowbase = (((size_t)(n * DOUT + d)) * DOUT + hrow) * (DOUT * COUT);
        #pragma unroll
        for (int fi = 0; fi < 2; ++fi) {
            const int fr   = nfp * 2 + fi;
            const int cout = fr * 32 + col;
            float ls = 0.f, lsq = 0.f;
            #pragma unroll
            for (int reg = 0; reg < 16; ++reg) {
                const int wout = (reg & 3) + 8 * (reg >> 2) + 4 * hi;
                float v = fmaxf(acc[mt][fi][reg], 0.0f);
                if (wout < DOUT) {
                    y[rowbase + (size_t)wout * COUT + cout] = v;
                    ls += v; lsq += v * v;
                }
            }
            // cohort sharing one GN group: same (col>>4) -> xor {1,2,4,8,32}
            #pragma unroll
            for (int off = 1; off < 16; off <<= 1) {
                ls  += __shfl_xor(ls, off);
                lsq += __shfl_xor(lsq, off);
            }
            ls  += __shfl_xor(ls, 32);
            lsq += __shfl_xor(lsq, 32);
            if (lane == 0 || lane == 16) {
                const int g = fr * 2 + (col >> 4);   // 8 groups of 16 couts
                atomicAdd(&gsum[g], ls);
                atomicAdd(&gsq[g], lsq);
            }
        }
    }
    __syncthreads();
    if (tid < NGRP) {
        atomicAdd(&stats[(n * NGRP + tid) * 2 + 0], gsum[tid]);
        atomicAdd(&stats[(n * NGRP + tid) * 2 + 1], gsq[tid]);
    }
}

// ---- elementwise normalize ----
__global__ __launch_bounds__(256) void gn_apply_kernel(
    float* __restrict__ y, const float* __restrict__ stats,
    const float* __restrict__ scale, const float* __restrict__ bias)
{
    const int total4 = N_ * DOUT * DOUT * DOUT * (COUT / 4);
    int i = blockIdx.x * 256 + threadIdx.x;
    if (i >= total4) return;

    const int t  = i & 31;
    const int co = t * 4;
    const int g  = t >> 2;
    const int n  = i / (DOUT * DOUT * DOUT * (COUT / 4));

    const float s  = stats[(n * NGRP + g) * 2 + 0];
    const float sq = stats[(n * NGRP + g) * 2 + 1];
    const float invN = 1.0f / (float)(DOUT * DOUT * DOUT * (COUT / NGRP));
    const float mean = s * invN;
    const float var  = sq * invN - mean * mean;
    const float rstd = rsqrtf(var + EPS);

    float4 v = ((float4*)y)[i];
    const float4 sc = *(const float4*)(scale + co);
    const float4 bi = *(const float4*)(bias + co);
    v.x = (v.x - mean) * rstd * sc.x + bi.x;
    v.y = (v.y - mean) * rstd * sc.y + bi.y;
    v.z = (v.z - mean) * rstd * sc.z + bi.z;
    v.w = (v.w - mean) * rstd * sc.w + bi.w;
    ((float4*)y)[i] = v;
}

extern "C" void kernel_launch(void* const* d_in, const int* in_sizes, int n_in,
                              void* d_out, int out_size, void* d_ws, size_t ws_size,
                              hipStream_t stream) {
    const float* x     = (const float*)d_in[0];
    const float* K     = (const float*)d_in[1];
    const float* scale = (const float*)d_in[2];
    const float* bias  = (const float*)d_in[3];
    float* y = (float*)d_out;

    float*    stats = (float*)((char*)d_ws + STATS_OFF);
    _Float16* Kf    = (_Float16*)((char*)d_ws + KF_OFF);

    convert_k_kernel<<<108, 256, 0, stream>>>(K, Kf, stats);
    conv_mfma_kernel<<<N_ * DOUT * 7, 256, 0, stream>>>(x, Kf, y, stats);
    const int total4 = N_ * DOUT * DOUT * DOUT * (COUT / 4);
    gn_apply_kernel<<<(total4 + 255) / 256, 256, 0, stream>>>(y, stats, scale, bias);
}